// Round 25
// baseline (155.851 us; speedup 1.0000x reference)
//
#include <hip/hip_runtime.h>
#include <hip/hip_bf16.h>
#include <cstdint>

#define S_LEN 1024
#define DMODEL 1024
#define NHEADS 16
#define DHEAD 64
#define MAXLEN 16384
#define BATCH 4

typedef __attribute__((ext_vector_type(8))) short bf16x8;
typedef __attribute__((ext_vector_type(4))) float f32x4;

#define AS1(p) ((const __attribute__((address_space(1))) unsigned int*)(p))
#define AS3(p) ((__attribute__((address_space(3))) unsigned int*)(p))

// RNE f32 -> bf16 bits
__device__ inline unsigned short f2b(float f) {
  unsigned int u = __float_as_uint(f);
  unsigned int r = (u + 0x7FFFu + ((u >> 16) & 1u)) >> 16;
  return (unsigned short)r;
}
__device__ inline float b2f(unsigned short u) {
  return __uint_as_float(((unsigned int)u) << 16);
}

// Swizzled LDS element index for [R][64] bf16 rows (128B): 8 slots of 16B, slot ^= row&7.
#define LDSWZ(row, slot) (((row) << 6) + (((slot) ^ ((row) & 7)) << 3))

// ---------------- Combined converts: z 0-2 = W transpose; z 3 = Er slice; z 4-6 = X.
__global__ __launch_bounds__(256) void convert_all(
    const float* __restrict__ W0, const float* __restrict__ W1, const float* __restrict__ W2,
    unsigned short* __restrict__ T0, unsigned short* __restrict__ T1, unsigned short* __restrict__ T2,
    const float* __restrict__ Er, unsigned short* __restrict__ Erb,
    const float* __restrict__ X0, const float* __restrict__ X1, const float* __restrict__ X2,
    unsigned short* __restrict__ B0, unsigned short* __restrict__ B1, unsigned short* __restrict__ B2) {
  const int z = blockIdx.z;
  if (z >= 4) {  // X convert: flat stream, 16 elts/thread
    const float* X = (z == 4) ? X0 : (z == 5) ? X1 : X2;
    unsigned short* B = (z == 4) ? B0 : (z == 5) ? B1 : B2;
    size_t i = (((size_t)blockIdx.y * 32 + blockIdx.x) * 256 + threadIdx.x) * 16;
    union { unsigned short hh[16]; int4 v[2]; } u;
#pragma unroll
    for (int r = 0; r < 4; ++r) {
      float4 f = *(const float4*)(X + i + r * 4);
      u.hh[r * 4 + 0] = f2b(f.x); u.hh[r * 4 + 1] = f2b(f.y);
      u.hh[r * 4 + 2] = f2b(f.z); u.hh[r * 4 + 3] = f2b(f.w);
    }
    *(int4*)(B + i) = u.v[0];
    *(int4*)(B + i + 8) = u.v[1];
    return;
  }
  if (z == 3) {  // Er: 1024x64 f32 -> bf16, 64 active blocks
    const int o = blockIdx.y * 32 + blockIdx.x;
    if (o < 64) {
      const int i = o * 1024 + threadIdx.x * 4;
      float4 f = *(const float4*)(Er + (size_t)(MAXLEN - S_LEN) * DHEAD + i);
      Erb[i] = f2b(f.x); Erb[i + 1] = f2b(f.y);
      Erb[i + 2] = f2b(f.z); Erb[i + 3] = f2b(f.w);
    }
    return;
  }
  const float* W = (z == 0) ? W0 : (z == 1) ? W1 : W2;
  unsigned short* WT = (z == 0) ? T0 : (z == 1) ? T1 : T2;
  __shared__ float t[32][33];
  const int bi = blockIdx.y * 32, bj = blockIdx.x * 32;
  const int r = threadIdx.x >> 3, c4 = (threadIdx.x & 7) * 4;
  float4 f = *(const float4*)&W[(size_t)(bi + r) * DMODEL + bj + c4];
  t[r][c4] = f.x; t[r][c4 + 1] = f.y; t[r][c4 + 2] = f.z; t[r][c4 + 3] = f.w;
  __syncthreads();
  ushort4 u;
  u.x = f2b(t[c4][r]); u.y = f2b(t[c4 + 1][r]);
  u.z = f2b(t[c4 + 2][r]); u.w = f2b(t[c4 + 3][r]);
  *(ushort4*)&WT[(size_t)(bj + r) * DMODEL + bi + c4] = u;
}

// ---------------- Projections, m97 structure (global_load_lds + pre-swizzled src).
// z==0 (q) output is pre-scaled by 0.125 (1/sqrt(dh)).
__global__ __launch_bounds__(256) void proj_glds3(
    const unsigned short* __restrict__ Xq, const unsigned short* __restrict__ Xk,
    const unsigned short* __restrict__ Xv,
    const unsigned short* __restrict__ T0, const unsigned short* __restrict__ T1,
    const unsigned short* __restrict__ T2,
    const float* __restrict__ b0, const float* __restrict__ b1, const float* __restrict__ b2,
    unsigned short* __restrict__ O0, unsigned short* __restrict__ O1,
    unsigned short* __restrict__ O2) {
  const int z = blockIdx.z;
  const unsigned short* X = (z == 0) ? Xq : (z == 1) ? Xk : Xv;
  const unsigned short* WT = (z == 0) ? T0 : (z == 1) ? T1 : T2;
  const float* bias = (z == 0) ? b0 : (z == 1) ? b1 : b2;
  unsigned short* Out = (z == 0) ? O0 : (z == 1) ? O1 : O2;
  const float osc = (z == 0) ? 0.125f : 1.0f;
  __shared__ unsigned short As[128 * 64];
  __shared__ unsigned short Bs[128 * 64];
  const int tid = threadIdx.x;
  const int l = tid & 63, w = tid >> 6;
  const int o = blockIdx.y * 8 + blockIdx.x;
  const int lid = (o & 7) * 32 + (o >> 3);
  const int bm = (lid >> 3) * 128, bn = (lid & 7) * 128;
  const int wr = (w >> 1) * 64, wc = (w & 1) * 64;
  const int lrow = l >> 3;
  const int slotlog = (l & 7) ^ (lrow & 7);
  const unsigned short* Xa = X + (size_t)(bm + lrow) * DMODEL + slotlog * 8;
  const unsigned short* Wa = WT + (size_t)(bn + lrow) * DMODEL + slotlog * 8;
  f32x4 acc[4][4] = {};
  for (int k0 = 0; k0 < DMODEL; k0 += 64) {
    __syncthreads();
#pragma unroll
    for (int j = 0; j < 4; ++j) {
      int r8 = (w * 4 + j) * 8;
      __builtin_amdgcn_global_load_lds(AS1(Xa + (size_t)r8 * DMODEL + k0),
                                       AS3(&As[(w * 4 + j) * 512]), 16, 0, 0);
      __builtin_amdgcn_global_load_lds(AS1(Wa + (size_t)r8 * DMODEL + k0),
                                       AS3(&Bs[(w * 4 + j) * 512]), 16, 0, 0);
    }
    __syncthreads();
#pragma unroll
    for (int ks = 0; ks < 2; ++ks) {
      bf16x8 a[4], b[4];
#pragma unroll
      for (int f = 0; f < 4; ++f) {
        int row = wr + f * 16 + (l & 15);
        a[f] = *(const bf16x8*)&As[LDSWZ(row, ks * 4 + (l >> 4))];
        int col = wc + f * 16 + (l & 15);
        b[f] = *(const bf16x8*)&Bs[LDSWZ(col, ks * 4 + (l >> 4))];
      }
#pragma unroll
      for (int i = 0; i < 4; ++i)
#pragma unroll
        for (int j = 0; j < 4; ++j)
          acc[i][j] = __builtin_amdgcn_mfma_f32_16x16x32_bf16(a[i], b[j], acc[i][j], 0, 0, 0);
    }
  }
#pragma unroll
  for (int i = 0; i < 4; ++i) {
    int m = bm + wr + i * 16 + ((l >> 4) << 2);
#pragma unroll
    for (int j = 0; j < 4; ++j) {
      int n = bn + wc + j * 16 + (l & 15);
      float bv = bias[n];
#pragma unroll
      for (int e = 0; e < 4; ++e)
        Out[(size_t)(m + e) * DMODEL + n] = f2b((acc[i][j][e] + bv) * osc);
    }
  }
}

// ---------------- V transpose (once): vtp[bh][dh][t] = vp[(b*S+t)*D + h*64+dh].
// 64x64 u16 LDS tile, pad 72 (16B-aligned rows). Coalesced global on both sides.
__global__ __launch_bounds__(256) void vt_transpose(const unsigned short* __restrict__ vp,
                                                    unsigned short* __restrict__ vtp) {
  const int bh = blockIdx.y;          // 0..63
  const int b = bh >> 4, h = bh & 15;
  const int t0 = blockIdx.x * 64;
  __shared__ unsigned short T[64 * 72];
  const int tid = threadIdx.x;
  const unsigned short* src = vp + ((size_t)(b * S_LEN + t0) * DMODEL) + h * DHEAD;
#pragma unroll
  for (int r = 0; r < 2; ++r) {
    int s = r * 256 + tid;            // 0..511
    int row = s >> 3, c8 = s & 7;     // row = t_local, 8-u16 chunk of dh
    *(int4*)&T[row * 72 + c8 * 8] = *(const int4*)(src + (size_t)row * DMODEL + c8 * 8);
  }
  __syncthreads();
  unsigned short* dst = vtp + (size_t)bh * (DHEAD * S_LEN) + t0;
#pragma unroll
  for (int r = 0; r < 2; ++r) {
    int o = r * 256 + tid;
    int dh = o >> 3, c8 = o & 7;      // out row dh, 8-u16 chunk of t
    union { unsigned short hh[8]; int4 v; } u;
#pragma unroll
    for (int k = 0; k < 8; ++k) u.hh[k] = T[(c8 * 8 + k) * 72 + dh];
    *(int4*)(dst + (size_t)dh * S_LEN + c8 * 8) = u.v;
  }
}

// ---------------- QEr with PRE-SKEWED scatter, branch-free flat address:
// value at (s, n) -> Gsk flat addr = 1025*s + n - 1023 (both skew branches agree;
// dropped iff addr < 0). bx==0 blocks zero the 128 diagonal holes Gsk[s][s+1].
__global__ __launch_bounds__(256) void qer_mfma(const unsigned short* __restrict__ qp,
    const unsigned short* __restrict__ Erb, unsigned short* __restrict__ G, int bh0) {
  const int bh = bh0 + blockIdx.z;
  const int b = bh >> 4, h = bh & 15;
  __shared__ unsigned short As[128 * 64];
  __shared__ unsigned short Bs[128 * 64];
  const int tid = threadIdx.x, l = tid & 63, wid = tid >> 6;
  const int bm = blockIdx.y * 128, bn = blockIdx.x * 128;
  const int wr = (wid >> 1) * 64, wc = (wid & 1) * 64;
  const unsigned short* qb = qp + (size_t)b * S_LEN * DMODEL + h * DHEAD;
  unsigned short* Gc = G + (size_t)blockIdx.z * S_LEN * S_LEN;
#pragma unroll
  for (int r = 0; r < 4; ++r) {
    int s = r * 256 + tid;
    int row = s >> 3, sl = s & 7;
    *(int4*)&As[LDSWZ(row, sl)] = *(const int4*)(qb + (size_t)(bm + row) * DMODEL + sl * 8);
    *(int4*)&Bs[LDSWZ(row, sl)] = *(const int4*)(Erb + (size_t)(bn + row) * DHEAD + sl * 8);
  }
  if (blockIdx.x == 0 && tid < 128) {
    int s = bm + tid;
    if (s < S_LEN - 1) Gc[(size_t)s * S_LEN + s + 1] = 0;
  }
  __syncthreads();
  f32x4 acc[4][4] = {};
#pragma unroll
  for (int ks = 0; ks < 2; ++ks) {
    bf16x8 a[4], b[4];
#pragma unroll
    for (int f = 0; f < 4; ++f) {
      int row = wr + f * 16 + (l & 15);
      a[f] = *(const bf16x8*)&As[LDSWZ(row, ks * 4 + (l >> 4))];
      int col = wc + f * 16 + (l & 15);
      b[f] = *(const bf16x8*)&Bs[LDSWZ(col, ks * 4 + (l >> 4))];
    }
#pragma unroll
    for (int i = 0; i < 4; ++i)
#pragma unroll
      for (int j = 0; j < 4; ++j)
        acc[i][j] = __builtin_amdgcn_mfma_f32_16x16x32_bf16(a[i], b[j], acc[i][j], 0, 0, 0);
  }
#pragma unroll
  for (int i = 0; i < 4; ++i) {
    int m = bm + wr + i * 16 + ((l >> 4) << 2);
#pragma unroll
    for (int j = 0; j < 4; ++j) {
      int n = bn + wc + j * 16 + (l & 15);
      int base = 1025 * m + n - 1023;  // flat skew addr at e=0
#pragma unroll
      for (int e = 0; e < 4; ++e) {
        int addr = base + 1025 * e;
        if (addr >= 0)
          Gc[addr] = f2b(acc[i][j][e]);
      }
    }
  }
}

// ---------------- Fused attention: r22 structure, V staged via global_load_lds
// from precomputed V^T (same pre-swizzled pattern as K; V-pack VALU deleted).
__global__ __launch_bounds__(256) void attn_skew(const unsigned short* __restrict__ qp,
    const unsigned short* __restrict__ kp, const unsigned short* __restrict__ vtp,
    const unsigned short* __restrict__ G, float* __restrict__ out, int bh0, int nb) {
  const int o = blockIdx.y * 16 + blockIdx.x;
  const int q8 = nb * 2;                     // nwg/8, nwg = 16*nb (%8==0 always)
  const int lid = (o & 7) * q8 + (o >> 3);   // bijection; XCD gets contiguous lids
  const int s0 = (lid & 15) * 64;
  const int bhl = lid >> 4;
  const int bh = bh0 + bhl;
  const int b = bh >> 4, h = bh & 15;
  __shared__ unsigned short Qs[64 * 64];
  __shared__ unsigned short Ks[64 * 64];
  __shared__ unsigned short Vt[64 * 64];
  __shared__ unsigned short Ps[4][16 * 64];
  const int tid = threadIdx.x, l = tid & 63, w = tid >> 6;
  const int lg = l >> 4, li = l & 15;
  const unsigned short* qb = qp + (size_t)b * S_LEN * DMODEL + h * DHEAD;
  const unsigned short* kb = kp + (size_t)b * S_LEN * DMODEL + h * DHEAD;
  const unsigned short* Gb = G + (size_t)bhl * S_LEN * S_LEN;

#pragma unroll
  for (int r = 0; r < 2; ++r) {
    int s = r * 256 + tid;
    int row = s >> 3, sl = s & 7;
    *(int4*)&Qs[LDSWZ(row, sl)] = *(const int4*)(qb + (size_t)(s0 + row) * DMODEL + sl * 8);
  }
  __syncthreads();
  bf16x8 qf[2];
#pragma unroll
  for (int ks = 0; ks < 2; ++ks)
    qf[ks] = *(const bf16x8*)&Qs[LDSWZ(w * 16 + li, ks * 4 + lg)];

  // Staging source pre-swizzle (linear gl_lds write == LDSWZ layout); identical
  // addressing shape for K (row = token, stride DMODEL) and V^T (row = dh,
  // stride S_LEN; per-tile offset moves along the row).
  const int lrow = l >> 3;
  const int chk = (l & 7) ^ lrow;
  const unsigned short* Ka = kb + (size_t)(w * 8 + lrow) * DMODEL + chk * 8;
  const unsigned short* Va = vtp + (size_t)bh * (DHEAD * S_LEN)
                               + (size_t)(w * 8 + lrow) * S_LEN + chk * 8;

  f32x4 o4[4] = {};
  float lsum[4] = {0.f, 0.f, 0.f, 0.f};
  int sg[4];
  const unsigned short* gp[4];
#pragma unroll
  for (int i = 0; i < 4; ++i) {
    sg[i] = s0 + w * 16 + (lg << 2) + i;
    gp[i] = Gb + (size_t)sg[i] * S_LEN + li;
  }
  const float L2E = 1.44269504f;
  const float SHF = 16.f * 1.44269504f;  // constant softmax shift (exp2 domain)

  for (int ti = 0; ti < 16; ++ti) {
    const int t0 = ti * 64;
    __syncthreads();  // prev tile's Ks/Vt readers done
    // --- stage K and V^T via global_load_lds (no VGPR round-trip, no pack)
    __builtin_amdgcn_global_load_lds(AS1(Ka + (size_t)t0 * DMODEL),
                                     AS3(&Ks[(w * 64) * 8]), 16, 0, 0);
    __builtin_amdgcn_global_load_lds(AS1(Ka + (size_t)(t0 + 32) * DMODEL),
                                     AS3(&Ks[(256 + w * 64) * 8]), 16, 0, 0);
    __builtin_amdgcn_global_load_lds(AS1(Va + t0),
                                     AS3(&Vt[(w * 64) * 8]), 16, 0, 0);
    __builtin_amdgcn_global_load_lds(AS1(Va + 32 * S_LEN + t0),
                                     AS3(&Vt[(256 + w * 64) * 8]), 16, 0, 0);
    __syncthreads();  // all 4 DMAs drained & visible
    // --- issue rel gathers (covered by QK below; L2-hot via XCD remap)
    unsigned short rv[4][4];
#pragma unroll
    for (int f = 0; f < 4; ++f)
#pragma unroll
      for (int i = 0; i < 4; ++i)
        rv[f][i] = gp[i][t0 + f * 16];
    // --- QK^T
    f32x4 sa[4] = {};
#pragma unroll
    for (int ks = 0; ks < 2; ++ks)
#pragma unroll
      for (int f = 0; f < 4; ++f) {
        bf16x8 kf = *(const bf16x8*)&Ks[LDSWZ(f * 16 + li, ks * 4 + lg)];
        sa[f] = __builtin_amdgcn_mfma_f32_16x16x32_bf16(qf[ks], kf, sa[f], 0, 0, 0);
      }
    // --- p = exp2((sa+rel)*log2e - SHF); truncate once, use for P and lsum
    unsigned short* Pw = &Ps[w][0];
#pragma unroll
    for (int f = 0; f < 4; ++f) {
#pragma unroll
      for (int i = 0; i < 4; ++i) {
        float sv = sa[f][i] + b2f(rv[f][i]);
        float pv = __builtin_exp2f(__builtin_fmaf(sv, L2E, -SHF));
        unsigned int pu = __float_as_uint(pv) & 0xffff0000u;
        lsum[i] += __uint_as_float(pu);
        int prow = (lg << 2) + i, pcol = f * 16 + li;
        Pw[LDSWZ(prow, pcol >> 3) + (pcol & 7)] = (unsigned short)(pu >> 16);
      }
    }
    // --- PV
#pragma unroll
    for (int ks = 0; ks < 2; ++ks) {
      bf16x8 pf = *(const bf16x8*)&Pw[LDSWZ(li, ks * 4 + lg)];
#pragma unroll
      for (int f = 0; f < 4; ++f) {
        bf16x8 vf = *(const bf16x8*)&Vt[LDSWZ(f * 16 + li, ks * 4 + lg)];
        o4[f] = __builtin_amdgcn_mfma_f32_16x16x32_bf16(pf, vf, o4[f], 0, 0, 0);
      }
    }
  }
  // ---- epilogue: single l reduction across the 16 lanes sharing each row
#pragma unroll
  for (int off = 8; off >= 1; off >>= 1)
#pragma unroll
    for (int i = 0; i < 4; ++i) lsum[i] += __shfl_xor(lsum[i], off);
#pragma unroll
  for (int i = 0; i < 4; ++i) {
    float inv = 1.f / lsum[i];
#pragma unroll
    for (int f = 0; f < 4; ++f)
      out[(size_t)(b * S_LEN + sg[i]) * DMODEL + h * DHEAD + f * 16 + li] = o4[f][i] * inv;
  }
}

extern "C" void kernel_launch(void* const* d_in, const int* in_sizes, int n_in,
                              void* d_out, int out_size, void* d_ws, size_t ws_size,
                              hipStream_t stream) {
  (void)in_sizes; (void)n_in; (void)out_size;
  const float* q_in = (const float*)d_in[0];
  const float* k_in = (const float*)d_in[1];
  const float* v_in = (const float*)d_in[2];
  const float* Wq   = (const float*)d_in[3];
  const float* bq   = (const float*)d_in[4];
  const float* Wk   = (const float*)d_in[5];
  const float* bk   = (const float*)d_in[6];
  const float* Wv   = (const float*)d_in[7];
  const float* bv   = (const float*)d_in[8];
  const float* Er   = (const float*)d_in[9];
  float* out = (float*)d_out;

  char* ws = (char*)d_ws;
  const size_t MB = (size_t)1 << 20;
  unsigned short* wtq = (unsigned short*)(ws);            // 2 MB
  unsigned short* wtk = (unsigned short*)(ws + 2 * MB);   // 2 MB
  unsigned short* wtv = (unsigned short*)(ws + 4 * MB);   // 2 MB
  unsigned short* erb = (unsigned short*)(ws + 6 * MB);   // 128 KB
  unsigned short* qp  = (unsigned short*)(ws + 8 * MB);   // 8 MB
  unsigned short* kp  = (unsigned short*)(ws + 16 * MB);  // 8 MB
  unsigned short* vp  = (unsigned short*)(ws + 24 * MB);  // 8 MB
  unsigned short* xq  = (unsigned short*)(ws + 32 * MB);  // 8 MB (bf16 X)
  unsigned short* xk  = (unsigned short*)(ws + 40 * MB);  // 8 MB
  unsigned short* xv  = (unsigned short*)(ws + 48 * MB);  // 8 MB
  unsigned short* vtp = (unsigned short*)(ws + 56 * MB);  // 8 MB (V transposed)
  unsigned short* G   = (unsigned short*)(ws + 64 * MB);  // nb * 2 MB

  const size_t gavail = (ws_size > 64 * MB) ? (ws_size - 64 * MB) : 0;
  int chunk = (int)(gavail / (2 * MB));
  if (chunk < 1) chunk = 1;
  if (chunk > 64) chunk = 64;

  dim3 blk(256);
  hipLaunchKernelGGL(convert_all, dim3(32, 32, 7), blk, 0, stream,
                     Wq, Wk, Wv, wtq, wtk, wtv, Er, erb,
                     q_in, k_in, v_in, xq, xk, xv);

  dim3 gproj(DMODEL / 128, (BATCH * S_LEN) / 128, 3);  // (8, 32, 3)
  hipLaunchKernelGGL(proj_glds3, gproj, blk, 0, stream,
                     xq, xk, xv, wtq, wtk, wtv, bq, bk, bv, qp, kp, vp);

  hipLaunchKernelGGL(vt_transpose, dim3(16, 64), blk, 0, stream, vp, vtp);

  for (int bh0 = 0; bh0 < BATCH * NHEADS; bh0 += chunk) {
    int nb = BATCH * NHEADS - bh0;
    if (nb > chunk) nb = chunk;
    dim3 gqer(S_LEN / 128, S_LEN / 128, nb);  // (8, 8, nb)
    hipLaunchKernelGGL(qer_mfma, gqer, blk, 0, stream, qp, erb, G, bh0);
    dim3 gattn(16, nb);                       // XCD-remapped inside
    hipLaunchKernelGGL(attn_skew, gattn, blk, 0, stream, qp, kp, vtp, G, out, bh0, nb);
  }
}

// Round 26
// 152.176 us; speedup vs baseline: 1.0242x; 1.0242x over previous
//
#include <hip/hip_runtime.h>
#include <hip/hip_bf16.h>
#include <cstdint>

#define S_LEN 1024
#define DMODEL 1024
#define NHEADS 16
#define DHEAD 64
#define MAXLEN 16384
#define BATCH 4

typedef __attribute__((ext_vector_type(8))) short bf16x8;
typedef __attribute__((ext_vector_type(4))) float f32x4;

#define AS1(p) ((const __attribute__((address_space(1))) unsigned int*)(p))
#define AS3(p) ((__attribute__((address_space(3))) unsigned int*)(p))

// RNE f32 -> bf16 bits
__device__ inline unsigned short f2b(float f) {
  unsigned int u = __float_as_uint(f);
  unsigned int r = (u + 0x7FFFu + ((u >> 16) & 1u)) >> 16;
  return (unsigned short)r;
}
__device__ inline float b2f(unsigned short u) {
  return __uint_as_float(((unsigned int)u) << 16);
}

// Swizzled LDS element index for [R][64] bf16 rows (128B): 8 slots of 16B, slot ^= row&7.
#define LDSWZ(row, slot) (((row) << 6) + (((slot) ^ ((row) & 7)) << 3))

// ---------------- Combined converts: z 0-2 = W transpose; z 3 = Er slice; z 4-6 = X.
__global__ __launch_bounds__(256) void convert_all(
    const float* __restrict__ W0, const float* __restrict__ W1, const float* __restrict__ W2,
    unsigned short* __restrict__ T0, unsigned short* __restrict__ T1, unsigned short* __restrict__ T2,
    const float* __restrict__ Er, unsigned short* __restrict__ Erb,
    const float* __restrict__ X0, const float* __restrict__ X1, const float* __restrict__ X2,
    unsigned short* __restrict__ B0, unsigned short* __restrict__ B1, unsigned short* __restrict__ B2) {
  const int z = blockIdx.z;
  if (z >= 4) {  // X convert: flat stream, 16 elts/thread
    const float* X = (z == 4) ? X0 : (z == 5) ? X1 : X2;
    unsigned short* B = (z == 4) ? B0 : (z == 5) ? B1 : B2;
    size_t i = (((size_t)blockIdx.y * 32 + blockIdx.x) * 256 + threadIdx.x) * 16;
    union { unsigned short hh[16]; int4 v[2]; } u;
#pragma unroll
    for (int r = 0; r < 4; ++r) {
      float4 f = *(const float4*)(X + i + r * 4);
      u.hh[r * 4 + 0] = f2b(f.x); u.hh[r * 4 + 1] = f2b(f.y);
      u.hh[r * 4 + 2] = f2b(f.z); u.hh[r * 4 + 3] = f2b(f.w);
    }
    *(int4*)(B + i) = u.v[0];
    *(int4*)(B + i + 8) = u.v[1];
    return;
  }
  if (z == 3) {  // Er: 1024x64 f32 -> bf16, 64 active blocks
    const int o = blockIdx.y * 32 + blockIdx.x;
    if (o < 64) {
      const int i = o * 1024 + threadIdx.x * 4;
      float4 f = *(const float4*)(Er + (size_t)(MAXLEN - S_LEN) * DHEAD + i);
      Erb[i] = f2b(f.x); Erb[i + 1] = f2b(f.y);
      Erb[i + 2] = f2b(f.z); Erb[i + 3] = f2b(f.w);
    }
    return;
  }
  const float* W = (z == 0) ? W0 : (z == 1) ? W1 : W2;
  unsigned short* WT = (z == 0) ? T0 : (z == 1) ? T1 : T2;
  __shared__ float t[32][33];
  const int bi = blockIdx.y * 32, bj = blockIdx.x * 32;
  const int r = threadIdx.x >> 3, c4 = (threadIdx.x & 7) * 4;
  float4 f = *(const float4*)&W[(size_t)(bi + r) * DMODEL + bj + c4];
  t[r][c4] = f.x; t[r][c4 + 1] = f.y; t[r][c4 + 2] = f.z; t[r][c4 + 3] = f.w;
  __syncthreads();
  ushort4 u;
  u.x = f2b(t[c4][r]); u.y = f2b(t[c4 + 1][r]);
  u.z = f2b(t[c4 + 2][r]); u.w = f2b(t[c4 + 3][r]);
  *(ushort4*)&WT[(size_t)(bj + r) * DMODEL + bi + c4] = u;
}

// ---------------- Projections, m97 structure (global_load_lds + pre-swizzled src).
// z==0 (q) output is pre-scaled by 0.125 (1/sqrt(dh)).
__global__ __launch_bounds__(256) void proj_glds3(
    const unsigned short* __restrict__ Xq, const unsigned short* __restrict__ Xk,
    const unsigned short* __restrict__ Xv,
    const unsigned short* __restrict__ T0, const unsigned short* __restrict__ T1,
    const unsigned short* __restrict__ T2,
    const float* __restrict__ b0, const float* __restrict__ b1, const float* __restrict__ b2,
    unsigned short* __restrict__ O0, unsigned short* __restrict__ O1,
    unsigned short* __restrict__ O2) {
  const int z = blockIdx.z;
  const unsigned short* X = (z == 0) ? Xq : (z == 1) ? Xk : Xv;
  const unsigned short* WT = (z == 0) ? T0 : (z == 1) ? T1 : T2;
  const float* bias = (z == 0) ? b0 : (z == 1) ? b1 : b2;
  unsigned short* Out = (z == 0) ? O0 : (z == 1) ? O1 : O2;
  const float osc = (z == 0) ? 0.125f : 1.0f;
  __shared__ unsigned short As[128 * 64];
  __shared__ unsigned short Bs[128 * 64];
  const int tid = threadIdx.x;
  const int l = tid & 63, w = tid >> 6;
  const int o = blockIdx.y * 8 + blockIdx.x;
  const int lid = (o & 7) * 32 + (o >> 3);
  const int bm = (lid >> 3) * 128, bn = (lid & 7) * 128;
  const int wr = (w >> 1) * 64, wc = (w & 1) * 64;
  const int lrow = l >> 3;
  const int slotlog = (l & 7) ^ (lrow & 7);
  const unsigned short* Xa = X + (size_t)(bm + lrow) * DMODEL + slotlog * 8;
  const unsigned short* Wa = WT + (size_t)(bn + lrow) * DMODEL + slotlog * 8;
  f32x4 acc[4][4] = {};
  for (int k0 = 0; k0 < DMODEL; k0 += 64) {
    __syncthreads();
#pragma unroll
    for (int j = 0; j < 4; ++j) {
      int r8 = (w * 4 + j) * 8;
      __builtin_amdgcn_global_load_lds(AS1(Xa + (size_t)r8 * DMODEL + k0),
                                       AS3(&As[(w * 4 + j) * 512]), 16, 0, 0);
      __builtin_amdgcn_global_load_lds(AS1(Wa + (size_t)r8 * DMODEL + k0),
                                       AS3(&Bs[(w * 4 + j) * 512]), 16, 0, 0);
    }
    __syncthreads();
#pragma unroll
    for (int ks = 0; ks < 2; ++ks) {
      bf16x8 a[4], b[4];
#pragma unroll
      for (int f = 0; f < 4; ++f) {
        int row = wr + f * 16 + (l & 15);
        a[f] = *(const bf16x8*)&As[LDSWZ(row, ks * 4 + (l >> 4))];
        int col = wc + f * 16 + (l & 15);
        b[f] = *(const bf16x8*)&Bs[LDSWZ(col, ks * 4 + (l >> 4))];
      }
#pragma unroll
      for (int i = 0; i < 4; ++i)
#pragma unroll
        for (int j = 0; j < 4; ++j)
          acc[i][j] = __builtin_amdgcn_mfma_f32_16x16x32_bf16(a[i], b[j], acc[i][j], 0, 0, 0);
    }
  }
#pragma unroll
  for (int i = 0; i < 4; ++i) {
    int m = bm + wr + i * 16 + ((l >> 4) << 2);
#pragma unroll
    for (int j = 0; j < 4; ++j) {
      int n = bn + wc + j * 16 + (l & 15);
      float bv = bias[n];
#pragma unroll
      for (int e = 0; e < 4; ++e)
        Out[(size_t)(m + e) * DMODEL + n] = f2b((acc[i][j][e] + bv) * osc);
    }
  }
}

// ---------------- QEr (pre-skewed scatter, flat address) + fused V transpose.
// blockIdx.x < 8 : qer for (bm = by*128, bn = bx*128) of bh = bh0 + z.
// blockIdx.x >= 8: V transpose chunk tchunk = (bx-8)*8 + by for bh = bh0 + z:
//   vtp[bh][dh][t] = vp[(b*S+t)*D + h*64+dh], 64x64 u16 LDS tile (pad 72).
// Flat skew addr = 1025*s + n - 1023 (dropped iff addr < 0).
// qer bx==0 blocks zero the 128 diagonal holes Gsk[s][s+1].
__global__ __launch_bounds__(256) void qer_vt(const unsigned short* __restrict__ qp,
    const unsigned short* __restrict__ Erb, const unsigned short* __restrict__ vp,
    unsigned short* __restrict__ vtp, unsigned short* __restrict__ G, int bh0) {
  const int bh = bh0 + blockIdx.z;
  const int b = bh >> 4, h = bh & 15;
  __shared__ unsigned short As[128 * 64];
  __shared__ unsigned short Bs[128 * 64];
  const int tid = threadIdx.x;

  if (blockIdx.x >= 8) {  // ---- V transpose path (reuses As as the 64x72 tile)
    const int tchunk = (blockIdx.x - 8) * 8 + blockIdx.y;  // 0..15
    const int t0 = tchunk * 64;
    unsigned short* T = As;  // 64*72 u16 = 9216 < 8192*... fits in As (8192 u16)? no:
    // 64*72 = 4608 u16 only (72 u16 per row) -> fits easily in As (8192 u16).
    const unsigned short* src = vp + ((size_t)(b * S_LEN + t0) * DMODEL) + h * DHEAD;
#pragma unroll
    for (int r = 0; r < 2; ++r) {
      int s = r * 256 + tid;
      int row = s >> 3, c8 = s & 7;
      *(int4*)&T[row * 72 + c8 * 8] = *(const int4*)(src + (size_t)row * DMODEL + c8 * 8);
    }
    __syncthreads();
    unsigned short* dst = vtp + (size_t)bh * (DHEAD * S_LEN) + t0;
#pragma unroll
    for (int r = 0; r < 2; ++r) {
      int o = r * 256 + tid;
      int dh = o >> 3, c8 = o & 7;
      union { unsigned short hh[8]; int4 v; } u;
#pragma unroll
      for (int k = 0; k < 8; ++k) u.hh[k] = T[(c8 * 8 + k) * 72 + dh];
      *(int4*)(dst + (size_t)dh * S_LEN + c8 * 8) = u.v;
    }
    return;
  }

  // ---- qer path (unchanged)
  const int l = tid & 63, wid = tid >> 6;
  const int bm = blockIdx.y * 128, bn = blockIdx.x * 128;
  const int wr = (wid >> 1) * 64, wc = (wid & 1) * 64;
  const unsigned short* qb = qp + (size_t)b * S_LEN * DMODEL + h * DHEAD;
  unsigned short* Gc = G + (size_t)blockIdx.z * S_LEN * S_LEN;
#pragma unroll
  for (int r = 0; r < 4; ++r) {
    int s = r * 256 + tid;
    int row = s >> 3, sl = s & 7;
    *(int4*)&As[LDSWZ(row, sl)] = *(const int4*)(qb + (size_t)(bm + row) * DMODEL + sl * 8);
    *(int4*)&Bs[LDSWZ(row, sl)] = *(const int4*)(Erb + (size_t)(bn + row) * DHEAD + sl * 8);
  }
  if (blockIdx.x == 0 && tid < 128) {
    int s = bm + tid;
    if (s < S_LEN - 1) Gc[(size_t)s * S_LEN + s + 1] = 0;
  }
  __syncthreads();
  f32x4 acc[4][4] = {};
#pragma unroll
  for (int ks = 0; ks < 2; ++ks) {
    bf16x8 a[4], b2[4];
#pragma unroll
    for (int f = 0; f < 4; ++f) {
      int row = wr + f * 16 + (l & 15);
      a[f] = *(const bf16x8*)&As[LDSWZ(row, ks * 4 + (l >> 4))];
      int col = wc + f * 16 + (l & 15);
      b2[f] = *(const bf16x8*)&Bs[LDSWZ(col, ks * 4 + (l >> 4))];
    }
#pragma unroll
    for (int i = 0; i < 4; ++i)
#pragma unroll
      for (int j = 0; j < 4; ++j)
        acc[i][j] = __builtin_amdgcn_mfma_f32_16x16x32_bf16(a[i], b2[j], acc[i][j], 0, 0, 0);
  }
#pragma unroll
  for (int i = 0; i < 4; ++i) {
    int m = bm + wr + i * 16 + ((l >> 4) << 2);
#pragma unroll
    for (int j = 0; j < 4; ++j) {
      int n = bn + wc + j * 16 + (l & 15);
      int base = 1025 * m + n - 1023;  // flat skew addr at e=0
#pragma unroll
      for (int e = 0; e < 4; ++e) {
        int addr = base + 1025 * e;
        if (addr >= 0)
          Gc[addr] = f2b(acc[i][j][e]);
      }
    }
  }
}

// ---------------- Fused attention: r25 structure (K and V^T both via
// global_load_lds with pre-swizzled sources; static-shift softmax; XCD remap).
__global__ __launch_bounds__(256) void attn_skew(const unsigned short* __restrict__ qp,
    const unsigned short* __restrict__ kp, const unsigned short* __restrict__ vtp,
    const unsigned short* __restrict__ G, float* __restrict__ out, int bh0, int nb) {
  const int o = blockIdx.y * 16 + blockIdx.x;
  const int q8 = nb * 2;                     // nwg/8, nwg = 16*nb (%8==0 always)
  const int lid = (o & 7) * q8 + (o >> 3);   // bijection; XCD gets contiguous lids
  const int s0 = (lid & 15) * 64;
  const int bhl = lid >> 4;
  const int bh = bh0 + bhl;
  const int b = bh >> 4, h = bh & 15;
  __shared__ unsigned short Qs[64 * 64];
  __shared__ unsigned short Ks[64 * 64];
  __shared__ unsigned short Vt[64 * 64];
  __shared__ unsigned short Ps[4][16 * 64];
  const int tid = threadIdx.x, l = tid & 63, w = tid >> 6;
  const int lg = l >> 4, li = l & 15;
  const unsigned short* qb = qp + (size_t)b * S_LEN * DMODEL + h * DHEAD;
  const unsigned short* kb = kp + (size_t)b * S_LEN * DMODEL + h * DHEAD;
  const unsigned short* Gb = G + (size_t)bhl * S_LEN * S_LEN;

#pragma unroll
  for (int r = 0; r < 2; ++r) {
    int s = r * 256 + tid;
    int row = s >> 3, sl = s & 7;
    *(int4*)&Qs[LDSWZ(row, sl)] = *(const int4*)(qb + (size_t)(s0 + row) * DMODEL + sl * 8);
  }
  __syncthreads();
  bf16x8 qf[2];
#pragma unroll
  for (int ks = 0; ks < 2; ++ks)
    qf[ks] = *(const bf16x8*)&Qs[LDSWZ(w * 16 + li, ks * 4 + lg)];

  // Staging source pre-swizzle (linear gl_lds write == LDSWZ layout)
  const int lrow = l >> 3;
  const int chk = (l & 7) ^ lrow;
  const unsigned short* Ka = kb + (size_t)(w * 8 + lrow) * DMODEL + chk * 8;
  const unsigned short* Va = vtp + (size_t)bh * (DHEAD * S_LEN)
                               + (size_t)(w * 8 + lrow) * S_LEN + chk * 8;

  f32x4 o4[4] = {};
  float lsum[4] = {0.f, 0.f, 0.f, 0.f};
  int sg[4];
  const unsigned short* gp[4];
#pragma unroll
  for (int i = 0; i < 4; ++i) {
    sg[i] = s0 + w * 16 + (lg << 2) + i;
    gp[i] = Gb + (size_t)sg[i] * S_LEN + li;
  }
  const float L2E = 1.44269504f;
  const float SHF = 16.f * 1.44269504f;  // constant softmax shift (exp2 domain)

  for (int ti = 0; ti < 16; ++ti) {
    const int t0 = ti * 64;
    __syncthreads();  // prev tile's Ks/Vt readers done
    // --- stage K and V^T via global_load_lds (no VGPR round-trip, no pack)
    __builtin_amdgcn_global_load_lds(AS1(Ka + (size_t)t0 * DMODEL),
                                     AS3(&Ks[(w * 64) * 8]), 16, 0, 0);
    __builtin_amdgcn_global_load_lds(AS1(Ka + (size_t)(t0 + 32) * DMODEL),
                                     AS3(&Ks[(256 + w * 64) * 8]), 16, 0, 0);
    __builtin_amdgcn_global_load_lds(AS1(Va + t0),
                                     AS3(&Vt[(w * 64) * 8]), 16, 0, 0);
    __builtin_amdgcn_global_load_lds(AS1(Va + 32 * S_LEN + t0),
                                     AS3(&Vt[(256 + w * 64) * 8]), 16, 0, 0);
    __syncthreads();  // all 4 DMAs drained & visible
    // --- issue rel gathers (covered by QK below; L2-hot via XCD remap)
    unsigned short rv[4][4];
#pragma unroll
    for (int f = 0; f < 4; ++f)
#pragma unroll
      for (int i = 0; i < 4; ++i)
        rv[f][i] = gp[i][t0 + f * 16];
    // --- QK^T
    f32x4 sa[4] = {};
#pragma unroll
    for (int ks = 0; ks < 2; ++ks)
#pragma unroll
      for (int f = 0; f < 4; ++f) {
        bf16x8 kf = *(const bf16x8*)&Ks[LDSWZ(f * 16 + li, ks * 4 + lg)];
        sa[f] = __builtin_amdgcn_mfma_f32_16x16x32_bf16(qf[ks], kf, sa[f], 0, 0, 0);
      }
    // --- p = exp2((sa+rel)*log2e - SHF); truncate once, use for P and lsum
    unsigned short* Pw = &Ps[w][0];
#pragma unroll
    for (int f = 0; f < 4; ++f) {
#pragma unroll
      for (int i = 0; i < 4; ++i) {
        float sv = sa[f][i] + b2f(rv[f][i]);
        float pv = __builtin_exp2f(__builtin_fmaf(sv, L2E, -SHF));
        unsigned int pu = __float_as_uint(pv) & 0xffff0000u;
        lsum[i] += __uint_as_float(pu);
        int prow = (lg << 2) + i, pcol = f * 16 + li;
        Pw[LDSWZ(prow, pcol >> 3) + (pcol & 7)] = (unsigned short)(pu >> 16);
      }
    }
    // --- PV
#pragma unroll
    for (int ks = 0; ks < 2; ++ks) {
      bf16x8 pf = *(const bf16x8*)&Pw[LDSWZ(li, ks * 4 + lg)];
#pragma unroll
      for (int f = 0; f < 4; ++f) {
        bf16x8 vf = *(const bf16x8*)&Vt[LDSWZ(f * 16 + li, ks * 4 + lg)];
        o4[f] = __builtin_amdgcn_mfma_f32_16x16x32_bf16(pf, vf, o4[f], 0, 0, 0);
      }
    }
  }
  // ---- epilogue: single l reduction across the 16 lanes sharing each row
#pragma unroll
  for (int off = 8; off >= 1; off >>= 1)
#pragma unroll
    for (int i = 0; i < 4; ++i) lsum[i] += __shfl_xor(lsum[i], off);
#pragma unroll
  for (int i = 0; i < 4; ++i) {
    float inv = 1.f / lsum[i];
#pragma unroll
    for (int f = 0; f < 4; ++f)
      out[(size_t)(b * S_LEN + sg[i]) * DMODEL + h * DHEAD + f * 16 + li] = o4[f][i] * inv;
  }
}

extern "C" void kernel_launch(void* const* d_in, const int* in_sizes, int n_in,
                              void* d_out, int out_size, void* d_ws, size_t ws_size,
                              hipStream_t stream) {
  (void)in_sizes; (void)n_in; (void)out_size;
  const float* q_in = (const float*)d_in[0];
  const float* k_in = (const float*)d_in[1];
  const float* v_in = (const float*)d_in[2];
  const float* Wq   = (const float*)d_in[3];
  const float* bq   = (const float*)d_in[4];
  const float* Wk   = (const float*)d_in[5];
  const float* bk   = (const float*)d_in[6];
  const float* Wv   = (const float*)d_in[7];
  const float* bv   = (const float*)d_in[8];
  const float* Er   = (const float*)d_in[9];
  float* out = (float*)d_out;

  char* ws = (char*)d_ws;
  const size_t MB = (size_t)1 << 20;
  unsigned short* wtq = (unsigned short*)(ws);            // 2 MB
  unsigned short* wtk = (unsigned short*)(ws + 2 * MB);   // 2 MB
  unsigned short* wtv = (unsigned short*)(ws + 4 * MB);   // 2 MB
  unsigned short* erb = (unsigned short*)(ws + 6 * MB);   // 128 KB
  unsigned short* qp  = (unsigned short*)(ws + 8 * MB);   // 8 MB
  unsigned short* kp  = (unsigned short*)(ws + 16 * MB);  // 8 MB
  unsigned short* vp  = (unsigned short*)(ws + 24 * MB);  // 8 MB
  unsigned short* xq  = (unsigned short*)(ws + 32 * MB);  // 8 MB (bf16 X)
  unsigned short* xk  = (unsigned short*)(ws + 40 * MB);  // 8 MB
  unsigned short* xv  = (unsigned short*)(ws + 48 * MB);  // 8 MB
  unsigned short* vtp = (unsigned short*)(ws + 56 * MB);  // 8 MB (V transposed)
  unsigned short* G   = (unsigned short*)(ws + 64 * MB);  // nb * 2 MB

  const size_t gavail = (ws_size > 64 * MB) ? (ws_size - 64 * MB) : 0;
  int chunk = (int)(gavail / (2 * MB));
  if (chunk < 1) chunk = 1;
  if (chunk > 64) chunk = 64;

  dim3 blk(256);
  hipLaunchKernelGGL(convert_all, dim3(32, 32, 7), blk, 0, stream,
                     Wq, Wk, Wv, wtq, wtk, wtv, Er, erb,
                     q_in, k_in, v_in, xq, xk, xv);

  dim3 gproj(DMODEL / 128, (BATCH * S_LEN) / 128, 3);  // (8, 32, 3)
  hipLaunchKernelGGL(proj_glds3, gproj, blk, 0, stream,
                     xq, xk, xv, wtq, wtk, wtv, bq, bk, bv, qp, kp, vp);

  for (int bh0 = 0; bh0 < BATCH * NHEADS; bh0 += chunk) {
    int nb = BATCH * NHEADS - bh0;
    if (nb > chunk) nb = chunk;
    dim3 gqer(10, 8, nb);  // x<8: qer tiles; x in {8,9}: V-transpose chunks
    hipLaunchKernelGGL(qer_vt, gqer, blk, 0, stream, qp, erb, vp, vtp, G, bh0);
    dim3 gattn(16, nb);    // XCD-remapped inside
    hipLaunchKernelGGL(attn_skew, gattn, blk, 0, stream, qp, kp, vtp, G, out, bh0, nb);
  }
}